// Round 2
// baseline (170.410 us; speedup 1.0000x reference)
//
#include <hip/hip_runtime.h>

// Problem constants from the reference: x is (N, T, F) fp32.
constexpr int N_ = 64;
constexpr int T_ = 4096;
constexpr int F_ = 64;
constexpr int F4 = F_ / 4;            // 16 float4 per (n,t) row
constexpr int ROWS_PER_BLOCK = 32;    // 8 lanes/row * 32 rows = 256 threads

// Native clang vector type: __builtin_nontemporal_store requires a pointer
// to scalar/vector-of-scalar, not HIP's struct float4.
typedef float floatx4 __attribute__((ext_vector_type(4)));

// Reflect-pad + validity-mask gather.
//   src = rel<0 ? -rel : (rel<L ? rel : 2L-rel-2), clipped to [0, T-1]
//   out[n,t,:] = t < L+p0+p1 ? x[n,src,:] : 0
//
// Layout v2: 8 lanes per (n,t) row, each lane owns 32 B (two consecutive
// float4). A wave covers 8 consecutive t-rows -> 2 KB contiguous store per
// wave. Two independent 16 B loads/stores per lane (second folds into an
// offset:16 immediate) double memory-level parallelism vs v1, and the src
// reflect arithmetic runs once per lane instead of once per 16 B.
// Stores are nontemporal: out is write-once/never-read; keep the 100 MB
// write stream from evicting the gather-read lines in L2.
__global__ __launch_bounds__(256) void pad_variable_kernel(
    const floatx4* __restrict__ x,
    const int*     __restrict__ lens,
    const int*     __restrict__ pad,  // (2, N) row-major: pad[0][n]=pad[n], pad[1][n]=pad[N_+n]
    floatx4*       __restrict__ out,
    int Tp)
{
    const int tid  = threadIdx.x;
    const int f8   = tid & 7;             // which 32B chunk within the row
    const int trow = tid >> 3;            // 0..31: which t-row in this block
    const int n    = blockIdx.y;          // wave-uniform -> lens/pad become s_loads

    const int L   = lens[n];
    const int p0  = pad[n];
    const int lim = L + p0 + pad[N_ + n]; // valid iff t < lim

    const int t = blockIdx.x * ROWS_PER_BLOCK + trow;
    if (t >= Tp) return;

    const int rel = t - p0;
    int src = (rel < 0) ? -rel : ((rel < L) ? rel : (2 * L - rel - 2));
    src = min(max(src, 0), T_ - 1);

    floatx4 v0 = (floatx4)0.f;
    floatx4 v1 = (floatx4)0.f;
    if (t < lim) {
        const floatx4* __restrict__ xr =
            x + (size_t)n * (T_ * F4) + (size_t)src * F4 + f8 * 2;
        v0 = xr[0];                       // global_load_dwordx4
        v1 = xr[1];                       // ... offset:16, independent
    }

    floatx4* __restrict__ orow =
        out + (size_t)n * Tp * F4 + (size_t)t * F4 + f8 * 2;
    __builtin_nontemporal_store(v0, &orow[0]);   // global_store_dwordx4 nt
    __builtin_nontemporal_store(v1, &orow[1]);   // ... offset:16 nt
}

extern "C" void kernel_launch(void* const* d_in, const int* in_sizes, int n_in,
                              void* d_out, int out_size, void* d_ws, size_t ws_size,
                              hipStream_t stream) {
    const float* x    = (const float*)d_in[0];
    const int*   lens = (const int*)d_in[1];
    const int*   pad  = (const int*)d_in[2];
    // d_in[3] is the Tp scalar on device; recover Tp from out_size instead
    // (out has N*Tp*F elements) so no device->host transfer is needed.
    const int Tp = out_size / (N_ * F_);

    dim3 block(256);
    dim3 grid((Tp + ROWS_PER_BLOCK - 1) / ROWS_PER_BLOCK, N_);
    hipLaunchKernelGGL(pad_variable_kernel, grid, block, 0, stream,
                       (const floatx4*)x, lens, pad, (floatx4*)d_out, Tp);
}

// Round 3
// 147.350 us; speedup vs baseline: 1.1565x; 1.1565x over previous
//
#include <hip/hip_runtime.h>

// Problem constants from the reference: x is (N, T, F) fp32.
constexpr int N_ = 64;
constexpr int T_ = 4096;
constexpr int F_ = 64;
constexpr int F4 = F_ / 4;            // 16 float4 per (n,t) row
constexpr int ROWS_PER_BLOCK = 32;    // 8 lanes/row * 32 rows = 256 threads

// Reflect-pad + validity-mask gather.
//   src = rel<0 ? -rel : (rel<L ? rel : 2L-rel-2), clipped to [0, T-1]
//   out[n,t,:] = t < L+p0+p1 ? x[n,src,:] : 0
//
// Layout: 8 lanes per (n,t) row, each lane owns 32 B (two consecutive
// float4). A wave covers 8 consecutive t-rows -> 2 KB contiguous store per
// wave. Two independent 16 B loads/stores per lane (second folds into an
// offset:16 immediate) for memory-level parallelism; src reflect arithmetic
// runs once per 32 B instead of once per 16 B.
//
// NOTE (round 2 post-mortem): __builtin_nontemporal_store regressed this
// kernel 34 -> 59.5 us with WRITE_SIZE inflated 100 -> 153 MB: the nt bit
// bypasses L2 write-combining, causing sub-line HBM writes + RMW. Dense
// contiguous streaming stores must go through L2 on gfx950.
__global__ __launch_bounds__(256) void pad_variable_kernel(
    const float4* __restrict__ x,
    const int*    __restrict__ lens,
    const int*    __restrict__ pad,   // (2, N) row-major: pad[0][n]=pad[n], pad[1][n]=pad[N_+n]
    float4*       __restrict__ out,
    int Tp)
{
    const int tid  = threadIdx.x;
    const int f8   = tid & 7;             // which 32B chunk within the row
    const int trow = tid >> 3;            // 0..31: which t-row in this block
    const int n    = blockIdx.y;          // wave-uniform -> lens/pad become s_loads

    const int L   = lens[n];
    const int p0  = pad[n];
    const int lim = L + p0 + pad[N_ + n]; // valid iff t < lim

    const int t = blockIdx.x * ROWS_PER_BLOCK + trow;
    if (t >= Tp) return;

    const int rel = t - p0;
    int src = (rel < 0) ? -rel : ((rel < L) ? rel : (2 * L - rel - 2));
    src = min(max(src, 0), T_ - 1);

    float4 v0 = make_float4(0.f, 0.f, 0.f, 0.f);
    float4 v1 = v0;
    if (t < lim) {
        const float4* __restrict__ xr =
            x + (size_t)n * (T_ * F4) + (size_t)src * F4 + f8 * 2;
        v0 = xr[0];                       // global_load_dwordx4
        v1 = xr[1];                       // ... offset:16, independent
    }

    float4* __restrict__ orow =
        out + (size_t)n * Tp * F4 + (size_t)t * F4 + f8 * 2;
    orow[0] = v0;                         // global_store_dwordx4 (through L2)
    orow[1] = v1;                         // ... offset:16
}

extern "C" void kernel_launch(void* const* d_in, const int* in_sizes, int n_in,
                              void* d_out, int out_size, void* d_ws, size_t ws_size,
                              hipStream_t stream) {
    const float* x    = (const float*)d_in[0];
    const int*   lens = (const int*)d_in[1];
    const int*   pad  = (const int*)d_in[2];
    // d_in[3] is the Tp scalar on device; recover Tp from out_size instead
    // (out has N*Tp*F elements) so no device->host transfer is needed.
    const int Tp = out_size / (N_ * F_);

    dim3 block(256);
    dim3 grid((Tp + ROWS_PER_BLOCK - 1) / ROWS_PER_BLOCK, N_);
    hipLaunchKernelGGL(pad_variable_kernel, grid, block, 0, stream,
                       (const float4*)x, lens, pad, (float4*)d_out, Tp);
}